// Round 11
// baseline (807.747 us; speedup 1.0000x reference)
//
#include <hip/hip_runtime.h>
#include <stdint.h>

#define HW 262144          // 512*512
#define LDIM 33

typedef __bf16 bf16x8 __attribute__((ext_vector_type(8)));
typedef __bf16 bf16x2 __attribute__((ext_vector_type(2)));
typedef float  f32x4  __attribute__((ext_vector_type(4)));

union BF8 { bf16x8 v; unsigned u[4]; };

// native f32->bf16 (RNE) — compiler fuses pairs into v_cvt_pk_bf16_f32
__device__ __forceinline__ unsigned pk2(float a, float b) {
  bf16x2 p; p[0] = (__bf16)a; p[1] = (__bf16)b;
  return __builtin_bit_cast(unsigned, p);
}
// hardware exp2: v_exp_f32 computes 2^x directly
__device__ __forceinline__ float exp2_hw(float x) {
  return __builtin_amdgcn_exp2f(x);
}
// tanh(x) = 1 - 2/(exp2(x*2*log2e)+1)
__device__ __forceinline__ float tanh_fast(float x) {
  float t = exp2_hw(x * 2.8853900818f);
  return 1.0f - __fdividef(2.0f, t + 1.0f);
}
// gelu_tanh(x) = x - x/(exp2(x*(2.3021667 + 0.1029425 x^2))+1)
__device__ __forceinline__ float gelu_t(float x) {
  float x2 = x * x;
  float p2 = x * fmaf(0.1029425216f, x2, 2.3021667f);
  float r  = __fdividef(1.0f, exp2_hw(p2) + 1.0f);
  return fmaf(-x, r, x);                                    // x(1 - r)
}

struct F3 { float x, y, z; };
__device__ __forceinline__ F3 lerp3(F3 a, F3 b, float f) {
  F3 r; r.x = a.x + f * (b.x - a.x); r.y = a.y + f * (b.y - a.y);
  r.z = a.z + f * (b.z - a.z); return r;
}

// issue the 64 raw ctx loads for one 32-px wave tile (fragment order)
__device__ __forceinline__ void load_raw(float (&raw)[2][4][8],
    const float* __restrict__ ctxB, int swb, int n, int q) {
  #pragma unroll
  for (int mt = 0; mt < 2; ++mt) {
    const int sA = swb + mt * 16 + n;
    #pragma unroll
    for (int ks = 0; ks < 4; ++ks) {
      const float* cb = ctxB + (size_t)(ks * 32 + q * 8) * HW + sA;
      #pragma unroll
      for (int j = 0; j < 8; ++j)
        raw[mt][ks][j] = cb[(size_t)j * HW];
    }
  }
}

// ============================ KERNEL 1: MLP offsets ============================
// 256 threads / 4 waves, 32 px per wave-iter, 4 iters (512 px/block).
// LDS map (65536 B):
//   [0,     32768)  W1 bf16: 128 rows x 256B, group kg stored at (kg ^ (row&15))
//   [32768, 49152)  W2 bf16:  64 rows x 256B, same swizzle
//   [49152, 65536)  per-wave h: 4 waves x 4096B (32 rows x 128B, swizz kg^(row&7))
// SOFTWARE PIPELINE: iteration i+1's 64 raw ctx loads are issued right after
// iteration i's fragments are packed -> ~900cy HBM latency hides under the
// GEMM1..GEMM3 compute span (the r10 null showed latency, not regs, is the cost).
// Live set ~200 VGPR -> needs the free-256 budget: 256-thread chassis with 64KB
// LDS keeps the allocator in the 2-blocks/CU / 256-reg regime (r0-proven; the
// 512-thread variant force-caps at 128 and spills, r5). Loop fully unrolled so
// the rotating raw buffer is SSA-renamed (never scratch).
__global__ __launch_bounds__(256, 2) void mlp_offset_kernel(
    const float* __restrict__ ctx,  const float* __restrict__ W1,
    const float* __restrict__ b1,   const float* __restrict__ W2,
    const float* __restrict__ b2,   const float* __restrict__ W3,
    const float* __restrict__ b3,   const float* __restrict__ oscp,
    float* __restrict__ out)
{
  __shared__ uint4 smem4[4096];
  char* sm = (char*)smem4;
  const int t    = threadIdx.x;
  const int lane = t & 63;
  const int wv   = t >> 6;        // wave 0..3
  const int n    = lane & 15;
  const int q    = lane >> 4;     // quad 0..3

  // ---- stage W1 (128x128) and W2 (64x128) to LDS as swizzled bf16 ----
  #pragma unroll
  for (int rep = 0; rep < 16; ++rep) {
    int f4 = t + 256 * rep;                 // float4 index 0..4095
    float4 v = ((const float4*)W1)[f4];
    int fi = f4 << 2;
    int o = fi >> 7, k = fi & 127;
    char* dst = sm + o * 256 + (((k >> 3) ^ (o & 15)) << 4) + ((k & 7) << 1);
    *(uint2*)dst = make_uint2(pk2(v.x, v.y), pk2(v.z, v.w));
  }
  #pragma unroll
  for (int rep = 0; rep < 8; ++rep) {
    int f4 = t + 256 * rep;                 // 0..2047
    float4 v = ((const float4*)W2)[f4];
    int fi = f4 << 2;
    int o = fi >> 7, k = fi & 127;
    char* dst = sm + 32768 + o * 256 + (((k >> 3) ^ (o & 15)) << 4) + ((k & 7) << 1);
    *(uint2*)dst = make_uint2(pk2(v.x, v.y), pk2(v.z, v.w));
  }
  __syncthreads();

  // per-lane constants
  float b1r[8];
  #pragma unroll
  for (int i = 0; i < 8; ++i) b1r[i] = b1[i * 16 + n];
  float b2r[4];
  #pragma unroll
  for (int i = 0; i < 4; ++i) b2r[i] = b2[i * 16 + n];
  // W3 padded 16x64 as a permanent A-fragment pair (rows 3..15 zero)
  BF8 w3a[2];
  #pragma unroll
  for (int ks3 = 0; ks3 < 2; ++ks3) {
    #pragma unroll
    for (int m = 0; m < 4; ++m) {
      float e0 = 0.f, e1 = 0.f;
      if (n < 3) {
        e0 = W3[n * 64 + ks3 * 32 + q * 8 + 2 * m];
        e1 = W3[n * 64 + ks3 * 32 + q * 8 + 2 * m + 1];
      }
      w3a[ks3].u[m] = pk2(e0, e1);
    }
  }
  const float b3a0 = b3[0], b3a1 = b3[1], b3a2 = b3[2];
  const float osc  = oscp[0];

  const int p0   = blockIdx.x * 512;        // 512 px per block, never crosses batch b
  const int bi   = p0 >> 18;
  const int sblk = p0 & (HW - 1);
  const float* ctxB = ctx + (size_t)bi * ((size_t)128 * HW);
  float*       outB = out + (size_t)bi * ((size_t)3 * HW);
  char* hb = sm + 49152 + wv * 4096;

  // ---- prologue: issue iteration 0's ctx loads ----
  float raw[2][4][8];
  load_raw(raw, ctxB, sblk + wv * 32, n, q);

  #pragma unroll
  for (int it = 0; it < 4; ++it) {
    const int sw = sblk + it * 128 + wv * 32;   // wave's 32-px base

    // ---- pack raw (iter it) into A1 fragments ----
    BF8 a1[2][4];
    #pragma unroll
    for (int mt = 0; mt < 2; ++mt)
      #pragma unroll
      for (int ks = 0; ks < 4; ++ks) {
        a1[mt][ks].u[0] = pk2(raw[mt][ks][0], raw[mt][ks][1]);
        a1[mt][ks].u[1] = pk2(raw[mt][ks][2], raw[mt][ks][3]);
        a1[mt][ks].u[2] = pk2(raw[mt][ks][4], raw[mt][ks][5]);
        a1[mt][ks].u[3] = pk2(raw[mt][ks][6], raw[mt][ks][7]);
      }

    // ---- PIPELINE: issue next iteration's loads now (latency hides under compute) ----
    if (it < 3)
      load_raw(raw, ctxB, sblk + (it + 1) * 128 + wv * 32, n, q);

    f32x4 acc2[2][4];
    #pragma unroll
    for (int mt = 0; mt < 2; ++mt)
      #pragma unroll
      for (int j = 0; j < 4; ++j) { f32x4 z = {0.f,0.f,0.f,0.f}; acc2[mt][j] = z; }

    #pragma unroll
    for (int half = 0; half < 2; ++half) {
      // ---- GEMM1 over 4 ntiles of this half (D[px][feat]) ----
      f32x4 acc1[2][4];
      #pragma unroll
      for (int mt = 0; mt < 2; ++mt)
        #pragma unroll
        for (int j = 0; j < 4; ++j) { f32x4 z = {0.f,0.f,0.f,0.f}; acc1[mt][j] = z; }

      #pragma unroll
      for (int ks = 0; ks < 4; ++ks) {
        #pragma unroll
        for (int nt4 = 0; nt4 < 4; ++nt4) {
          int row = (half * 4 + nt4) * 16 + n;
          bf16x8 bw = *(const bf16x8*)(sm + row * 256 + ((((ks << 2) + q) ^ n) << 4));
          acc1[0][nt4] = __builtin_amdgcn_mfma_f32_16x16x32_bf16(a1[0][ks].v, bw, acc1[0][nt4], 0, 0, 0);
          acc1[1][nt4] = __builtin_amdgcn_mfma_f32_16x16x32_bf16(a1[1][ks].v, bw, acc1[1][nt4], 0, 0, 0);
        }
      }
      // ---- h1 half: bias + gelu -> bf16 -> LDS (C/D -> A-fragment transpose) ----
      #pragma unroll
      for (int mt = 0; mt < 2; ++mt)
        #pragma unroll
        for (int nt4 = 0; nt4 < 4; ++nt4) {
          int fl = nt4 * 16 + n;        // feature within half, 0..63
          int kgf = fl >> 3;
          #pragma unroll
          for (int r = 0; r < 4; ++r) {
            int px = mt * 16 + (q << 2) + r;
            float hv = gelu_t(acc1[mt][nt4][r] + b1r[half * 4 + nt4]);
            *(__bf16*)(hb + px * 128 + ((kgf ^ (px & 7)) << 4) + ((fl & 7) << 1)) = (__bf16)hv;
          }
        }
      // ---- GEMM2 partial (D[px][feat2]) over this half's 64 feats ----
      #pragma unroll
      for (int ks2 = 0; ks2 < 2; ++ks2) {
        bf16x8 a2[2];
        #pragma unroll
        for (int mt = 0; mt < 2; ++mt) {
          int px = mt * 16 + n;
          a2[mt] = *(const bf16x8*)(hb + px * 128 + ((((ks2 << 2) + q) ^ (px & 7)) << 4));
        }
        #pragma unroll
        for (int nt2 = 0; nt2 < 4; ++nt2) {
          int row = nt2 * 16 + n;
          int kg2 = half * 8 + (ks2 << 2) + q;
          bf16x8 bw = *(const bf16x8*)(sm + 32768 + row * 256 + ((kg2 ^ n) << 4));
          acc2[0][nt2] = __builtin_amdgcn_mfma_f32_16x16x32_bf16(a2[0], bw, acc2[0][nt2], 0, 0, 0);
          acc2[1][nt2] = __builtin_amdgcn_mfma_f32_16x16x32_bf16(a2[1], bw, acc2[1][nt2], 0, 0, 0);
        }
      }
    }

    // ---- h2 = gelu(acc2 + b2) -> bf16 -> LDS [px][feat2] (swizzled) ----
    #pragma unroll
    for (int mt = 0; mt < 2; ++mt)
      #pragma unroll
      for (int nt2 = 0; nt2 < 4; ++nt2) {
        int kgW = (nt2 << 1) + (n >> 3);
        #pragma unroll
        for (int r = 0; r < 4; ++r) {
          int px = mt * 16 + (q << 2) + r;
          float hv = gelu_t(acc2[mt][nt2][r] + b2r[nt2]);
          *(__bf16*)(hb + px * 128 + ((kgW ^ (px & 7)) << 4) + ((n & 7) << 1)) = (__bf16)hv;
        }
      }

    // ---- GEMM3: D[ch][px] = W3pad(16x64) x h2^T, per 16-px group ----
    f32x4 acc3[2];
    #pragma unroll
    for (int mt = 0; mt < 2; ++mt) {
      f32x4 z = {0.f, 0.f, 0.f, 0.f};
      acc3[mt] = z;
      #pragma unroll
      for (int ks3 = 0; ks3 < 2; ++ks3) {
        int px = mt * 16 + n;
        bf16x8 hf = *(const bf16x8*)(hb + px * 128 + ((((ks3 << 2) + q) ^ (px & 7)) << 4));
        acc3[mt] = __builtin_amdgcn_mfma_f32_16x16x32_bf16(w3a[ks3].v, hf, acc3[mt], 0, 0, 0);
      }
    }
    // q=0 rows r=0..2 hold ch 0..2 for px=n(+16mt) -> redistribute to lane (n, q<3)
    const int ba = n << 2;
    float d00 = __int_as_float(__builtin_amdgcn_ds_bpermute(ba, __float_as_int(acc3[0][0])));
    float d01 = __int_as_float(__builtin_amdgcn_ds_bpermute(ba, __float_as_int(acc3[0][1])));
    float d02 = __int_as_float(__builtin_amdgcn_ds_bpermute(ba, __float_as_int(acc3[0][2])));
    float d10 = __int_as_float(__builtin_amdgcn_ds_bpermute(ba, __float_as_int(acc3[1][0])));
    float d11 = __int_as_float(__builtin_amdgcn_ds_bpermute(ba, __float_as_int(acc3[1][1])));
    float d12 = __int_as_float(__builtin_amdgcn_ds_bpermute(ba, __float_as_int(acc3[1][2])));

    // ---- store offsets to OUT (kernel 2 adds LUT sample): 48 lanes x 2 px ----
    if (q < 3) {
      float sel0 = (q == 0) ? d00 : ((q == 1) ? d01 : d02);
      float sel1 = (q == 0) ? d10 : ((q == 1) ? d11 : d12);
      float bsel = (q == 0) ? b3a0 : ((q == 1) ? b3a1 : b3a2);
      outB[q * HW + sw + n]      = tanh_fast(sel0 + bsel) * osc;
      outB[q * HW + sw + 16 + n] = tanh_fast(sel1 + bsel) * osc;
    }
  }
}

// ============================ KERNEL 2: LUT apply ============================
// Elementwise: out[px] = trilinear(lut, img[px])*2 - 1 + out[px]  (offset RMW).
__global__ __launch_bounds__(256) void lut_apply_kernel(
    const float* __restrict__ img, const float* __restrict__ lut,
    float* __restrict__ out)
{
  const int p  = blockIdx.x * 256 + threadIdx.x;   // 0 .. 4*HW-1 (exact grid)
  const int b  = p >> 18;
  const int sp = p & (HW - 1);
  const float* imgB = img + (size_t)b * ((size_t)3 * HW);
  float*       outB = out + (size_t)b * ((size_t)3 * HW);

  const float rr = imgB[sp];
  const float gg = imgB[HW + sp];
  const float bb = imgB[2 * HW + sp];
  const float o0 = outB[sp];
  const float o1 = outB[HW + sp];
  const float o2 = outB[2 * HW + sp];

  float gx = fminf(fmaxf(fmaf(rr, 16.f, 16.f), 0.f), 32.f);  // R -> x (b axis)
  float gy = fminf(fmaxf(fmaf(gg, 16.f, 16.f), 0.f), 32.f);  // G -> y (g axis)
  float gz = fminf(fmaxf(fmaf(bb, 16.f, 16.f), 0.f), 32.f);  // B -> z (r axis)
  int x0 = (int)gx, y0 = (int)gy, z0 = (int)gz;
  float fx = gx - (float)x0, fy = gy - (float)y0, fz = gz - (float)z0;
  int x1 = min(x0 + 1, 32), y1 = min(y0 + 1, 32), z1 = min(z0 + 1, 32);
  int zy00 = (z0 * LDIM + y0) * LDIM, zy01 = (z0 * LDIM + y1) * LDIM;
  int zy10 = (z1 * LDIM + y0) * LDIM, zy11 = (z1 * LDIM + y1) * LDIM;
  const F3* L3 = (const F3*)lut;
  F3 c000 = L3[zy00 + x0], c001 = L3[zy00 + x1];
  F3 c010 = L3[zy01 + x0], c011 = L3[zy01 + x1];
  F3 c100 = L3[zy10 + x0], c101 = L3[zy10 + x1];
  F3 c110 = L3[zy11 + x0], c111 = L3[zy11 + x1];
  F3 c00 = lerp3(c000, c001, fx), c01 = lerp3(c010, c011, fx);
  F3 c10 = lerp3(c100, c101, fx), c11 = lerp3(c110, c111, fx);
  F3 ca  = lerp3(c00, c01, fy),   cb2 = lerp3(c10, c11, fy);
  F3 so  = lerp3(ca, cb2, fz);
  outB[sp]          = fmaf(so.x, 2.f, -1.f) + o0;
  outB[HW + sp]     = fmaf(so.y, 2.f, -1.f) + o1;
  outB[2 * HW + sp] = fmaf(so.z, 2.f, -1.f) + o2;
}

extern "C" void kernel_launch(void* const* d_in, const int* in_sizes, int n_in,
                              void* d_out, int out_size, void* d_ws, size_t ws_size,
                              hipStream_t stream) {
  const float* img = (const float*)d_in[0];
  const float* ctx = (const float*)d_in[1];
  const float* lut = (const float*)d_in[2];
  const float* W1  = (const float*)d_in[3];
  const float* b1  = (const float*)d_in[4];
  const float* W2  = (const float*)d_in[5];
  const float* b2  = (const float*)d_in[6];
  const float* W3  = (const float*)d_in[7];
  const float* b3  = (const float*)d_in[8];
  const float* osc = (const float*)d_in[9];
  float* out = (float*)d_out;
  // Pass 1: MLP offsets -> out. 2048 blocks x 512 px; 256 thr (4 waves),
  // 64 KB LDS -> 2 blocks/CU, free 256-reg budget, pipelined ctx loads.
  mlp_offset_kernel<<<dim3(2048), dim3(256), 0, stream>>>(
      ctx, W1, b1, W2, b2, W3, b3, osc, out);
  // Pass 2: LUT sample + combine (in-place RMW on out). 4096 x 256.
  lut_apply_kernel<<<dim3(4096), dim3(256), 0, stream>>>(img, lut, out);
}

// Round 12
// 777.285 us; speedup vs baseline: 1.0392x; 1.0392x over previous
//
#include <hip/hip_runtime.h>
#include <stdint.h>

#define HW 262144          // 512*512
#define LDIM 33

typedef __bf16 bf16x8 __attribute__((ext_vector_type(8)));
typedef __bf16 bf16x2 __attribute__((ext_vector_type(2)));
typedef float  f32x4  __attribute__((ext_vector_type(4)));

union BF8 { bf16x8 v; unsigned u[4]; };

// native f32->bf16 (RNE) — compiler fuses pairs into v_cvt_pk_bf16_f32
__device__ __forceinline__ unsigned pk2(float a, float b) {
  bf16x2 p; p[0] = (__bf16)a; p[1] = (__bf16)b;
  return __builtin_bit_cast(unsigned, p);
}
// hardware exp2: v_exp_f32 computes 2^x directly
__device__ __forceinline__ float exp2_hw(float x) {
  return __builtin_amdgcn_exp2f(x);
}
// tanh(x) = 1 - 2/(exp2(x*2*log2e)+1)
__device__ __forceinline__ float tanh_fast(float x) {
  float t = exp2_hw(x * 2.8853900818f);
  return 1.0f - __fdividef(2.0f, t + 1.0f);
}
// gelu_tanh(x) = x - x/(exp2(x*(2.3021667 + 0.1029425 x^2))+1)
__device__ __forceinline__ float gelu_t(float x) {
  float x2 = x * x;
  float p2 = x * fmaf(0.1029425216f, x2, 2.3021667f);
  float r  = __fdividef(1.0f, exp2_hw(p2) + 1.0f);
  return fmaf(-x, r, x);                                    // x(1 - r)
}

// LDS map (57344 B, 256 threads / 4 waves — free-budget no-spill chassis):
//   [0,     32768)  W1 bf16: 128 rows x 256B, 16B group kg stored at (kg ^ (row&15))
//   [32768, 49152)  W2 bf16:  64 rows x 256B, same swizzle
//   [49152, 57344)  per-wave h: 4 waves x 2048B (16 px rows x 128B, swizz kg^(px&7))
//
// KEY CHANGE (r12): GEMM1 and GEMM2 are operand-SWAPPED — mfma(W_frag, x_frag).
// A- and B-fragments share the same lane->(idx,k) map, so the swap changes no
// addresses; but C/D now holds h[feat = q*4+r][px = n]: each lane's 4 acc values
// are 4 CONSECUTIVE features at one px = 8 contiguous LDS bytes -> ONE
// ds_write_b64 replaces FOUR ds_write_b16 (h1: 32->8, h2: 16->4 writes/iter).
// Biases become per-(q,r): b1l[8][4]+b2l[4][4] (+40 regs, fine at free budget).
// Live set ~165 -> launch_bounds(256,2) free 256-reg budget, no spill;
// occupancy LDS-capped at 2 blocks/CU (bet = shorter critical path, not TLP).
__global__ __launch_bounds__(256, 2) void local3dlut_kernel(
    const float* __restrict__ img,  const float* __restrict__ ctx,
    const float* __restrict__ lut,  const float* __restrict__ W1,
    const float* __restrict__ b1,   const float* __restrict__ W2,
    const float* __restrict__ b2,   const float* __restrict__ W3,
    const float* __restrict__ b3,   const float* __restrict__ oscp,
    float* __restrict__ out)
{
  __shared__ uint4 smem4[3584];
  char* sm = (char*)smem4;
  const int t    = threadIdx.x;
  const int lane = t & 63;
  const int wv   = t >> 6;        // wave 0..3
  const int n    = lane & 15;
  const int q    = lane >> 4;     // quad 0..3

  // ---- stage W1 (128x128) and W2 (64x128) to LDS as swizzled bf16 ----
  #pragma unroll
  for (int rep = 0; rep < 16; ++rep) {
    int f4 = t + 256 * rep;                 // float4 index 0..4095
    float4 v = ((const float4*)W1)[f4];
    int fi = f4 << 2;
    int o = fi >> 7, k = fi & 127;
    char* dst = sm + o * 256 + (((k >> 3) ^ (o & 15)) << 4) + ((k & 7) << 1);
    *(uint2*)dst = make_uint2(pk2(v.x, v.y), pk2(v.z, v.w));
  }
  #pragma unroll
  for (int rep = 0; rep < 8; ++rep) {
    int f4 = t + 256 * rep;                 // 0..2047
    float4 v = ((const float4*)W2)[f4];
    int fi = f4 << 2;
    int o = fi >> 7, k = fi & 127;
    char* dst = sm + 32768 + o * 256 + (((k >> 3) ^ (o & 15)) << 4) + ((k & 7) << 1);
    *(uint2*)dst = make_uint2(pk2(v.x, v.y), pk2(v.z, v.w));
  }
  __syncthreads();

  // per-lane constants (swapped layout: biases indexed by feat = blk*16 + q*4 + r)
  float b1l[8][4];
  #pragma unroll
  for (int i = 0; i < 8; ++i)
    #pragma unroll
    for (int r = 0; r < 4; ++r) b1l[i][r] = b1[i * 16 + (q << 2) + r];
  float b2l[4][4];
  #pragma unroll
  for (int i = 0; i < 4; ++i)
    #pragma unroll
    for (int r = 0; r < 4; ++r) b2l[i][r] = b2[i * 16 + (q << 2) + r];
  // W3 padded 16x64 as a permanent A-fragment pair (rows 3..15 zero)
  BF8 w3a[2];
  #pragma unroll
  for (int ks3 = 0; ks3 < 2; ++ks3) {
    #pragma unroll
    for (int m = 0; m < 4; ++m) {
      float e0 = 0.f, e1 = 0.f;
      if (n < 3) {
        e0 = W3[n * 64 + ks3 * 32 + q * 8 + 2 * m];
        e1 = W3[n * 64 + ks3 * 32 + q * 8 + 2 * m + 1];
      }
      w3a[ks3].u[m] = pk2(e0, e1);
    }
  }
  const float b3a0 = b3[0], b3a1 = b3[1], b3a2 = b3[2];
  const float osc  = oscp[0];

  const int p0   = blockIdx.x * 512;        // 512 px per block, never crosses batch b
  const int bi   = p0 >> 18;
  const int sblk = p0 & (HW - 1);
  const float* ctxB = ctx + (size_t)bi * ((size_t)128 * HW);
  const float* imgB = img + (size_t)bi * ((size_t)3 * HW);
  float*       outB = out + (size_t)bi * ((size_t)3 * HW);
  char* hb = sm + 49152 + wv * 2048;
  // per-lane h-row base (px = n) with swizzle precomputed pieces
  char* hrow = hb + n * 128;
  const int nsw = n & 7;
  const int woff = (q & 1) << 3;            // 8B half within the 16B group

  #pragma unroll 1
  for (int it = 0; it < 8; ++it) {
    const int sw = sblk + it * 64 + wv * 16;   // wave's 16-px base in image

    // img loads for this lane's tail pixel (px = n)
    const int spf = sw + n;
    const float rr = imgB[spf];
    const float gg = imgB[HW + spf];
    const float bb = imgB[2 * HW + spf];

    // ---- A1 fragments: ctx, 4 ksteps (global, fragment order) ----
    BF8 a1[4];
    {
      const int sA = sw + n;
      #pragma unroll
      for (int ks = 0; ks < 4; ++ks) {
        const float* cb = ctxB + (size_t)(ks * 32 + q * 8) * HW + sA;
        float v0 = cb[0];
        float v1 = cb[(size_t)1 * HW];
        float v2 = cb[(size_t)2 * HW];
        float v3 = cb[(size_t)3 * HW];
        float v4 = cb[(size_t)4 * HW];
        float v5 = cb[(size_t)5 * HW];
        float v6 = cb[(size_t)6 * HW];
        float v7 = cb[(size_t)7 * HW];
        a1[ks].u[0] = pk2(v0, v1);
        a1[ks].u[1] = pk2(v2, v3);
        a1[ks].u[2] = pk2(v4, v5);
        a1[ks].u[3] = pk2(v6, v7);
      }
    }

    // ---- EARLY LUT: indices + all 8 corner gathers issued now; L2 latency
    //      hides under GEMM1..GEMM3. All lanes gather (ch clamped for q==3). ----
    float fx, fy, fz;
    float c000, c001, c010, c011, c100, c101, c110, c111;
    {
      float gx = fminf(fmaxf(fmaf(rr, 16.f, 16.f), 0.f), 32.f);  // R -> x (b axis)
      float gy = fminf(fmaxf(fmaf(gg, 16.f, 16.f), 0.f), 32.f);  // G -> y (g axis)
      float gz = fminf(fmaxf(fmaf(bb, 16.f, 16.f), 0.f), 32.f);  // B -> z (r axis)
      int x0 = (int)gx, y0 = (int)gy, z0 = (int)gz;
      fx = gx - (float)x0; fy = gy - (float)y0; fz = gz - (float)z0;
      int x1 = min(x0 + 1, 32), y1 = min(y0 + 1, 32), z1 = min(z0 + 1, 32);
      int zy00 = (z0 * LDIM + y0) * LDIM, zy01 = (z0 * LDIM + y1) * LDIM;
      int zy10 = (z1 * LDIM + y0) * LDIM, zy11 = (z1 * LDIM + y1) * LDIM;
      const int chq = (q < 3) ? q : 2;
      const float* L = lut;
      c000 = L[(zy00 + x0) * 3 + chq]; c001 = L[(zy00 + x1) * 3 + chq];
      c010 = L[(zy01 + x0) * 3 + chq]; c011 = L[(zy01 + x1) * 3 + chq];
      c100 = L[(zy10 + x0) * 3 + chq]; c101 = L[(zy10 + x1) * 3 + chq];
      c110 = L[(zy11 + x0) * 3 + chq]; c111 = L[(zy11 + x1) * 3 + chq];
    }

    f32x4 acc2[4];
    #pragma unroll
    for (int j = 0; j < 4; ++j) { f32x4 z = {0.f,0.f,0.f,0.f}; acc2[j] = z; }

    #pragma unroll
    for (int half = 0; half < 2; ++half) {
      // ---- GEMM1 (SWAPPED): D[feat = q*4+r][px = n] ----
      f32x4 acc1[4];
      #pragma unroll
      for (int j = 0; j < 4; ++j) { f32x4 z = {0.f,0.f,0.f,0.f}; acc1[j] = z; }

      #pragma unroll
      for (int ks = 0; ks < 4; ++ks) {
        #pragma unroll
        for (int nt4 = 0; nt4 < 4; ++nt4) {
          int row = (half * 4 + nt4) * 16 + n;
          bf16x8 bw = *(const bf16x8*)(sm + row * 256 + ((((ks << 2) + q) ^ n) << 4));
          acc1[nt4] = __builtin_amdgcn_mfma_f32_16x16x32_bf16(bw, a1[ks].v, acc1[nt4], 0, 0, 0);
        }
      }
      // ---- h1: bias+gelu, pack 4 consecutive feats -> ONE ds_write_b64 per nt4 ----
      #pragma unroll
      for (int nt4 = 0; nt4 < 4; ++nt4) {
        float g0 = gelu_t(acc1[nt4][0] + b1l[half * 4 + nt4][0]);
        float g1 = gelu_t(acc1[nt4][1] + b1l[half * 4 + nt4][1]);
        float g2 = gelu_t(acc1[nt4][2] + b1l[half * 4 + nt4][2]);
        float g3 = gelu_t(acc1[nt4][3] + b1l[half * 4 + nt4][3]);
        int kg = (nt4 << 1) + (q >> 1);       // 16B feature group within 128B row
        char* dst = hrow + ((kg ^ nsw) << 4) + woff;
        *(uint2*)dst = make_uint2(pk2(g0, g1), pk2(g2, g3));
      }
      // ---- GEMM2 (SWAPPED) partial: D[feat2 = q*4+r][px = n] ----
      #pragma unroll
      for (int ks2 = 0; ks2 < 2; ++ks2) {
        bf16x8 a2 = *(const bf16x8*)(hrow + ((((ks2 << 2) + q) ^ nsw) << 4));
        #pragma unroll
        for (int nt2 = 0; nt2 < 4; ++nt2) {
          int row = nt2 * 16 + n;
          int kg2 = half * 8 + (ks2 << 2) + q;
          bf16x8 bw = *(const bf16x8*)(sm + 32768 + row * 256 + ((kg2 ^ n) << 4));
          acc2[nt2] = __builtin_amdgcn_mfma_f32_16x16x32_bf16(bw, a2, acc2[nt2], 0, 0, 0);
        }
      }
    }

    // ---- h2: bias+gelu, packed b64 writes (4 total) ----
    #pragma unroll
    for (int nt2 = 0; nt2 < 4; ++nt2) {
      float g0 = gelu_t(acc2[nt2][0] + b2l[nt2][0]);
      float g1 = gelu_t(acc2[nt2][1] + b2l[nt2][1]);
      float g2 = gelu_t(acc2[nt2][2] + b2l[nt2][2]);
      float g3 = gelu_t(acc2[nt2][3] + b2l[nt2][3]);
      int kg = (nt2 << 1) + (q >> 1);
      char* dst = hrow + ((kg ^ nsw) << 4) + woff;
      *(uint2*)dst = make_uint2(pk2(g0, g1), pk2(g2, g3));
    }

    // ---- GEMM3: D[ch][px] = W3pad(16x64) x h2 ----
    f32x4 acc3 = {0.f, 0.f, 0.f, 0.f};
    #pragma unroll
    for (int ks3 = 0; ks3 < 2; ++ks3) {
      bf16x8 hf = *(const bf16x8*)(hrow + ((((ks3 << 2) + q) ^ nsw) << 4));
      acc3 = __builtin_amdgcn_mfma_f32_16x16x32_bf16(w3a[ks3].v, hf, acc3, 0, 0, 0);
    }
    // q=0 rows r=0..2 hold ch 0..2 for px=n -> redistribute to lane (n, q<3)
    const int ba = n << 2;
    float d0 = __int_as_float(__builtin_amdgcn_ds_bpermute(ba, __float_as_int(acc3[0])));
    float d1 = __int_as_float(__builtin_amdgcn_ds_bpermute(ba, __float_as_int(acc3[1])));
    float d2 = __int_as_float(__builtin_amdgcn_ds_bpermute(ba, __float_as_int(acc3[2])));

    // ---- tail: 48 lanes, ch = q (q<3), px = n; corners + offset in-register ----
    if (q < 3) {
      float sel  = (q == 0) ? d0   : ((q == 1) ? d1   : d2);
      float bsel = (q == 0) ? b3a0 : ((q == 1) ? b3a1 : b3a2);
      float ov = tanh_fast(sel + bsel) * osc;

      float c00 = c000 + fx * (c001 - c000);
      float c01 = c010 + fx * (c011 - c010);
      float c10 = c100 + fx * (c101 - c100);
      float c11 = c110 + fx * (c111 - c110);
      float ca  = c00 + fy * (c01 - c00);
      float cb2 = c10 + fy * (c11 - c10);
      float so  = ca + fz * (cb2 - ca);
      outB[q * HW + sw + n] = so * 2.f - 1.f + ov;
    }
  }
}

extern "C" void kernel_launch(void* const* d_in, const int* in_sizes, int n_in,
                              void* d_out, int out_size, void* d_ws, size_t ws_size,
                              hipStream_t stream) {
  const float* img = (const float*)d_in[0];
  const float* ctx = (const float*)d_in[1];
  const float* lut = (const float*)d_in[2];
  const float* W1  = (const float*)d_in[3];
  const float* b1  = (const float*)d_in[4];
  const float* W2  = (const float*)d_in[5];
  const float* b2  = (const float*)d_in[6];
  const float* W3  = (const float*)d_in[7];
  const float* b3  = (const float*)d_in[8];
  const float* osc = (const float*)d_in[9];
  float* out = (float*)d_out;
  // 2048 blocks x 512 px; 256 threads (4 waves), 56 KB LDS -> 2 blocks/CU,
  // free 256-reg budget (no spill), swapped-GEMM packed-b64 transpose path
  local3dlut_kernel<<<dim3(2048), dim3(256), 0, stream>>>(
      img, ctx, lut, W1, b1, W2, b2, W3, b3, osc, out);
}